// Round 5
// baseline (76.283 us; speedup 1.0000x reference)
//
#include <hip/hip_runtime.h>
#include <hip/hip_bf16.h>
#include <stdint.h>

#define HW 192
#define NC 128
#define KEPS 1e-5f

typedef __attribute__((ext_vector_type(8))) short short8;
typedef __attribute__((ext_vector_type(4))) float f32x4;

__device__ __forceinline__ float max3f(float a, float b, float c) {
  float d;
  asm("v_max3_f32 %0, %1, %2, %3" : "=v"(d) : "v"(a), "v"(b), "v"(c));
  return d;
}

// ---------------------------------------------------------------------------
// Prep: f32 [n][C][HW] -> bf16 [n][HW][C] via LDS transpose (coalesced both
// sides). probT XOR-swizzled within each 256B row: byte col = (2c)^((hw&7)<<4).
// 512 blocks = 128 slices x 4 c-chunks of 32.
// ---------------------------------------------------------------------------
__global__ __launch_bounds__(256)
void prep_kernel(const float* __restrict__ prob,
                 const float* __restrict__ gal,
                 unsigned short* __restrict__ probT,
                 unsigned short* __restrict__ galT) {
  __shared__ unsigned short lds[32 * 194];   // stride 194 ushort: bank-safe
  const int b = blockIdx.x;
  const int slice = b >> 2;
  const int cc = (b & 3) * 32;
  const bool isProbe = (slice < 64);
  const float* src = isProbe ? prob + (size_t)slice * NC * HW
                             : gal + (size_t)(slice - 64) * NC * HW;
  unsigned short* dst = isProbe ? probT + (size_t)slice * HW * NC
                                : galT + (size_t)(slice - 64) * HW * NC;
  // read phase: 32x192 f32, fully contiguous from src + cc*HW
  const float* s0 = src + (size_t)cc * HW;
  #pragma unroll
  for (int k = 0; k < 24; ++k) {
    int i = k * 256 + threadIdx.x;        // 0..6143
    int cp = i / HW;                       // 0..31 (magic-mul)
    int hw = i - cp * HW;
    lds[cp * 194 + hw] =
        __builtin_bit_cast(unsigned short, __float2bfloat16(s0[i]));
  }
  __syncthreads();
  // write phase: thread t owns c' = t&31, hw = (t>>5) + 8k
  const int cp = threadIdx.x & 31;
  const int hw0 = threadIdx.x >> 5;
  const int c = cc + cp;
  #pragma unroll
  for (int k = 0; k < 24; ++k) {
    int hw = hw0 + 8 * k;
    unsigned short v = lds[cp * 194 + hw];
    int col = isProbe ? ((((2 * c) ^ ((hw & 7) << 4))) >> 1) : c;
    dst[hw * NC + col] = v;
  }
}

// ---------------------------------------------------------------------------
__device__ __forceinline__ void gl_lds16(const void* gsrc, void* ldst) {
  __builtin_amdgcn_global_load_lds(
      (const __attribute__((address_space(1))) void*)gsrc,
      (__attribute__((address_space(3))) void*)ldst, 16, 0, 0);
}

// DPP row_ror max within 16-lane rows (VALU pipe)
template <int CTRL>
__device__ __forceinline__ float dpp_max(float x) {
  int xi = __builtin_bit_cast(int, x);
  int yi = __builtin_amdgcn_update_dpp(xi, xi, CTRL, 0xf, 0xf, false);
  return fmaxf(x, __builtin_bit_cast(float, yi));
}
__device__ __forceinline__ float ror16_max(float x) {
  x = dpp_max<0x121>(x);
  x = dpp_max<0x122>(x);
  x = dpp_max<0x124>(x);
  x = dpp_max<0x128>(x);
  return x;
}

// ---------------------------------------------------------------------------
// Pair kernel: 1024 blocks = g*16 + pc (4 probes each); XCD = pc&7.
// Waves 2x2: wave (wr,wc) = gal rows wr*96..+95 (A in regs), probe cols
// wc*48..+47 of the 96-col half-tile. One barrier per t-step; cmPart
// parity-double-buffered; Wout deferred one step.
// ---------------------------------------------------------------------------
__global__ __launch_bounds__(256, 2)
void pair_kernel(const unsigned short* __restrict__ galT,
                 const unsigned short* __restrict__ probT,
                 const float* __restrict__ fc_w,
                 float* __restrict__ Wout,
                 float* __restrict__ sPart,
                 float* __restrict__ qPart) {
  __shared__ char ldsP[2][24576];        // double-buffered 96-col half-tile
  __shared__ float cmPart[2][2][96];     // [parity][wr][col-in-half]
  __shared__ float rmPart[2][192];       // [wc][gal row] (h==1 only)
  __shared__ float red[4];

  const int tid = threadIdx.x;
  const int lane = tid & 63;
  const int wid = tid >> 6;
  const int wr = wid >> 1;
  const int wc = wid & 1;
  const int q = lane >> 4;
  const int r16 = lane & 15;
  const int swz = (r16 & 7) << 4;

  const int g = blockIdx.x >> 4;
  const int pc = blockIdx.x & 15;        // 4 probes per block

  // persistent gallery A-frags: row = wr*96 + m*16 + r16
  const char* gbase = (const char*)(galT + (size_t)g * HW * NC);
  short8 a[6][4];
  #pragma unroll
  for (int m = 0; m < 6; ++m)
    #pragma unroll
    for (int ks = 0; ks < 4; ++ks)
      a[m][ks] = *(const short8*)(gbase + (wr * 96 + m * 16 + r16) * 256 + ks * 64 + q * 16);

  const float wcm0 = (tid < 96) ? fc_w[tid] : 0.f;
  const float wcm1 = (tid < 96) ? fc_w[96 + tid] : 0.f;
  const float wrmt = (tid < 192) ? fc_w[192 + tid] : 0.f;

  const char* pTbase = (const char*)probT;

  // stage half-tile 0
  {
    const char* src = pTbase + (size_t)(pc * 4) * 49152;
    #pragma unroll
    for (int c = 0; c < 6; ++c)
      gl_lds16(src + (wid * 6 + c) * 1024 + lane * 16, &ldsP[0][(wid * 6 + c) * 1024]);
  }
  __syncthreads();

  float s_acc = 0.f, q_acc = 0.f;
  float rm[6][4];
  float wp = 0.f;
  const f32x4 zz = (f32x4){0.f, 0.f, 0.f, 0.f};

  for (int t = 0; t < 8; ++t) {
    const int h = t & 1;
    const char* cur = ldsP[t & 1];

    if (t + 1 < 8) {  // async prefetch next half-tile
      const int tn = t + 1;
      const char* src = pTbase + (size_t)(pc * 4 + (tn >> 1)) * 49152 + (tn & 1) * 24576;
      char* dst = ldsP[tn & 1];
      #pragma unroll
      for (int c = 0; c < 6; ++c)
        gl_lds16(src + (wid * 6 + c) * 1024 + lane * 16, dst + (wid * 6 + c) * 1024);
    }
    if (h == 0) wp = 0.f;

    __builtin_amdgcn_s_setprio(1);
    f32x4 acc[6][3];
    #pragma unroll
    for (int n = 0; n < 3; ++n) {
      const char* rowB = cur + (wc * 48 + n * 16 + r16) * 256;
      {
        short8 bf = *(const short8*)(rowB + ((q * 16) ^ swz));
        #pragma unroll
        for (int m = 0; m < 6; ++m)
          acc[m][n] = __builtin_amdgcn_mfma_f32_16x16x32_bf16(a[m][0], bf, zz, 0, 0, 0);
      }
      #pragma unroll
      for (int ks = 1; ks < 4; ++ks) {
        short8 bf = *(const short8*)(rowB + ((ks * 64 + q * 16) ^ swz));
        #pragma unroll
        for (int m = 0; m < 6; ++m)
          acc[m][n] = __builtin_amdgcn_mfma_f32_16x16x32_bf16(a[m][ks], bf, acc[m][n], 0, 0, 0);
      }
    }
    __builtin_amdgcn_s_setprio(0);

    // ---- col-max over wave's 96 rows (max3 tree), cols = wc*48+n*16+r16 ----
    #pragma unroll
    for (int n = 0; n < 3; ++n) {
      float t8[8];
      #pragma unroll
      for (int k = 0; k < 8; ++k)
        t8[k] = max3f(acc[(3 * k) >> 2][n][(3 * k) & 3],
                      acc[(3 * k + 1) >> 2][n][(3 * k + 1) & 3],
                      acc[(3 * k + 2) >> 2][n][(3 * k + 2) & 3]);
      float u0 = max3f(t8[0], t8[1], t8[2]);
      float u1 = max3f(t8[3], t8[4], t8[5]);
      float u2 = fmaxf(t8[6], t8[7]);
      float cm = max3f(u0, u1, u2);
      cm = fmaxf(cm, __shfl_xor(cm, 16));
      cm = fmaxf(cm, __shfl_xor(cm, 32));
      if (lane < 16) cmPart[h][wr][wc * 48 + n * 16 + r16] = cm;
    }
    // ---- row-max lane partial (max3 over n); finish via DPP at h==1 ----
    #pragma unroll
    for (int m = 0; m < 6; ++m)
      #pragma unroll
      for (int j = 0; j < 4; ++j) {
        float v = max3f(acc[m][0][j], acc[m][1][j], acc[m][2][j]);
        rm[m][j] = h ? fmaxf(rm[m][j], v) : v;
      }
    if (h == 1) {
      #pragma unroll
      for (int m = 0; m < 6; ++m)
        #pragma unroll
        for (int j = 0; j < 4; ++j) {
          float v = ror16_max(rm[m][j]);
          if (r16 == j) rmPart[wc][wr * 96 + m * 16 + q * 4 + j] = v;
        }
    }
    __syncthreads();   // single barrier: partials + staged tile ready

    // ---- combine (reads parity-h cmPart; next step writes parity 1-h) ----
    if (t >= 2 && h == 0 && tid == 0) {   // deferred Wout flush (probe t/2-1)
      Wout[(pc * 4 + (t >> 1) - 1) * 64 + g] = red[0] + red[1] + red[2] + red[3];
    }
    if (tid < 96) {
      float cmf = fmaxf(cmPart[h][0][tid], cmPart[h][1][tid]);
      s_acc += cmf; q_acc += cmf * cmf;
      wp += cmf * (h ? wcm1 : wcm0);
    }
    if (h == 1) {
      if (tid < 192) {
        float rv = fmaxf(rmPart[0][tid], rmPart[1][tid]);
        s_acc += rv; q_acc += rv * rv;
        wp += rv * wrmt;
      }
      #pragma unroll
      for (int msk = 1; msk < 64; msk <<= 1) wp += __shfl_xor(wp, msk);
      if (lane == 0) red[wid] = wp;
    }
  }

  // epilogue: flush last probe's W, then block stats
  __syncthreads();
  if (tid == 0)
    Wout[(pc * 4 + 3) * 64 + g] = red[0] + red[1] + red[2] + red[3];
  #pragma unroll
  for (int msk = 1; msk < 64; msk <<= 1) {
    s_acc += __shfl_xor(s_acc, msk);
    q_acc += __shfl_xor(q_acc, msk);
  }
  if (lane == 0) { rmPart[0][wid] = s_acc; rmPart[0][4 + wid] = q_acc; }
  __syncthreads();
  if (tid == 0) {
    sPart[blockIdx.x] = rmPart[0][0] + rmPart[0][1] + rmPart[0][2] + rmPart[0][3];
    qPart[blockIdx.x] = rmPart[0][4] + rmPart[0][5] + rmPart[0][6] + rmPart[0][7];
  }
}

// ---------------------------------------------------------------------------
// Finalize: exact BN -> fc -> BN chain. One block, 1024 threads (sPart: 1024).
// ---------------------------------------------------------------------------
__device__ __forceinline__ float block_sum(float v, float* rbuf, float* bc, int nw) {
  int t = threadIdx.x, lane = t & 63, wid = t >> 6;
  #pragma unroll
  for (int m = 1; m < 64; m <<= 1) v += __shfl_xor(v, m);
  if (lane == 0) rbuf[wid] = v;
  __syncthreads();
  if (t == 0) {
    float r = 0.f;
    for (int i = 0; i < nw; ++i) r += rbuf[i];
    bc[0] = r;
  }
  __syncthreads();
  float res = bc[0];
  __syncthreads();
  return res;
}

__global__ __launch_bounds__(1024)
void finalize_kernel(const float* __restrict__ Wv,
                     const float* __restrict__ sPart,
                     const float* __restrict__ qPart,
                     const float* __restrict__ fc_w,
                     const float* __restrict__ fc_b,
                     const float* __restrict__ bn_g,
                     const float* __restrict__ bn_b,
                     const float* __restrict__ lbn_g,
                     const float* __restrict__ lbn_b,
                     float* __restrict__ out) {
  __shared__ float rbuf[16];
  __shared__ float bc[1];
  const int t = threadIdx.x;  // 1024

  float S = block_sum(sPart[t], rbuf, bc, 16);
  float Q = block_sum(qPart[t], rbuf, bc, 16);
  float SW = block_sum((t < 384) ? fc_w[t] : 0.f, rbuf, bc, 16);

  const float Nf = 4096.0f * 384.0f;
  float mu = S / Nf;
  float var = Q / Nf - mu * mu;
  float istd = rsqrtf(var + KEPS);
  float cA = istd * bn_g[0];
  float off = bn_b[0] * SW + fc_b[0] - cA * mu * SW;

  float l[4];
  float ls = 0.f;
  #pragma unroll
  for (int i = 0; i < 4; ++i) {
    int n = t + i * 1024;
    l[i] = cA * Wv[n] + off;
    ls += l[i];
  }
  float LS = block_sum(ls, rbuf, bc, 16);
  float lmu = LS / 4096.0f;
  float lq = 0.f;
  #pragma unroll
  for (int i = 0; i < 4; ++i) { float d = l[i] - lmu; lq += d * d; }
  float LQ = block_sum(lq, rbuf, bc, 16);
  float lvar = LQ / 4096.0f;
  float sc = lbn_g[0] * rsqrtf(lvar + KEPS);
  float lb = lbn_b[0];
  #pragma unroll
  for (int i = 0; i < 4; ++i) {
    int n = t + i * 1024;
    out[n] = (l[i] - lmu) * sc + lb;
  }
}

// ---------------------------------------------------------------------------
extern "C" void kernel_launch(void* const* d_in, const int* in_sizes, int n_in,
                              void* d_out, int out_size, void* d_ws, size_t ws_size,
                              hipStream_t stream) {
  const float* prob  = (const float*)d_in[0];
  const float* gal   = (const float*)d_in[1];
  const float* bn_g  = (const float*)d_in[2];
  const float* bn_b  = (const float*)d_in[3];
  const float* fc_w  = (const float*)d_in[4];
  const float* fc_b  = (const float*)d_in[5];
  const float* lbn_g = (const float*)d_in[6];
  const float* lbn_b = (const float*)d_in[7];
  float* out = (float*)d_out;

  char* ws = (char*)d_ws;
  unsigned short* probT = (unsigned short*)(ws);            // 3,145,728 B
  unsigned short* galT  = (unsigned short*)(ws + 3145728);  // 3,145,728 B
  float* Wv    = (float*)(ws + 6291456);                    // 16384 B
  float* sPart = (float*)(ws + 6307840);                    // 4096 B
  float* qPart = (float*)(ws + 6311936);                    // 4096 B

  prep_kernel<<<512, 256, 0, stream>>>(prob, gal, probT, galT);
  pair_kernel<<<1024, 256, 0, stream>>>(galT, probT, fc_w, Wv, sPart, qPart);
  finalize_kernel<<<1, 1024, 0, stream>>>(Wv, sPart, qPart, fc_w, fc_b,
                                          bn_g, bn_b, lbn_g, lbn_b, out);
}

// Round 6
// 69.963 us; speedup vs baseline: 1.0903x; 1.0903x over previous
//
#include <hip/hip_runtime.h>
#include <hip/hip_bf16.h>
#include <stdint.h>

#define HW 192
#define NC 128
#define KEPS 1e-5f
#define QTB 12288   /* 48-col quarter tile bytes */

typedef __attribute__((ext_vector_type(8))) short short8;
typedef __attribute__((ext_vector_type(4))) float f32x4;

__device__ __forceinline__ float max3f(float a, float b, float c) {
  float d;
  asm("v_max3_f32 %0, %1, %2, %3" : "=v"(d) : "v"(a), "v"(b), "v"(c));
  return d;
}

// ---------------------------------------------------------------------------
// Prep: f32 [n][C][HW] -> bf16 [n][HW][C] via LDS transpose (coalesced both
// sides). probT XOR-swizzled within each 256B row: byte col = (2c)^((hw&7)<<4).
// ---------------------------------------------------------------------------
__global__ __launch_bounds__(256)
void prep_kernel(const float* __restrict__ prob,
                 const float* __restrict__ gal,
                 unsigned short* __restrict__ probT,
                 unsigned short* __restrict__ galT) {
  __shared__ unsigned short lds[32 * 194];
  const int b = blockIdx.x;
  const int slice = b >> 2;
  const int cc = (b & 3) * 32;
  const bool isProbe = (slice < 64);
  const float* src = isProbe ? prob + (size_t)slice * NC * HW
                             : gal + (size_t)(slice - 64) * NC * HW;
  unsigned short* dst = isProbe ? probT + (size_t)slice * HW * NC
                                : galT + (size_t)(slice - 64) * HW * NC;
  const float* s0 = src + (size_t)cc * HW;
  #pragma unroll
  for (int k = 0; k < 24; ++k) {
    int i = k * 256 + threadIdx.x;
    int cp = i / HW;
    int hw = i - cp * HW;
    lds[cp * 194 + hw] =
        __builtin_bit_cast(unsigned short, __float2bfloat16(s0[i]));
  }
  __syncthreads();
  const int cp = threadIdx.x & 31;
  const int hw0 = threadIdx.x >> 5;
  const int c = cc + cp;
  #pragma unroll
  for (int k = 0; k < 24; ++k) {
    int hw = hw0 + 8 * k;
    unsigned short v = lds[cp * 194 + hw];
    int col = isProbe ? ((((2 * c) ^ ((hw & 7) << 4))) >> 1) : c;
    dst[hw * NC + col] = v;
  }
}

// ---------------------------------------------------------------------------
__device__ __forceinline__ void gl_lds16(const void* gsrc, void* ldst) {
  __builtin_amdgcn_global_load_lds(
      (const __attribute__((address_space(1))) void*)gsrc,
      (__attribute__((address_space(3))) void*)ldst, 16, 0, 0);
}

template <int CTRL>
__device__ __forceinline__ float dpp_max(float x) {
  int xi = __builtin_bit_cast(int, x);
  int yi = __builtin_amdgcn_update_dpp(xi, xi, CTRL, 0xf, 0xf, false);
  return fmaxf(x, __builtin_bit_cast(float, yi));
}
__device__ __forceinline__ float ror16_max(float x) {
  x = dpp_max<0x121>(x);
  x = dpp_max<0x122>(x);
  x = dpp_max<0x124>(x);
  x = dpp_max<0x128>(x);
  return x;
}

// ---------------------------------------------------------------------------
// Pair kernel: 1024 blocks = g*16 + pc (4 probes each). 4 waves = 4 gal-row
// groups of 48 (A persistent in regs, 48 VGPR). Step = 48-col quarter tile
// (12KB, double-buffered, async gl_lds). acc = 9 f32x4. One barrier/step;
// all max partials go to per-probe LDS; single combine phase at block end.
// launch_bounds(256,3) -> 3 blocks/CU, 3 de-phased streams.
// ---------------------------------------------------------------------------
__global__ __launch_bounds__(256, 3)
void pair_kernel(const unsigned short* __restrict__ galT,
                 const unsigned short* __restrict__ probT,
                 const float* __restrict__ fc_w,
                 float* __restrict__ Wout,
                 float* __restrict__ sPart,
                 float* __restrict__ qPart) {
  __shared__ char ldsP[2][QTB];       // double-buffered quarter tile
  __shared__ float cmP[4][4][192];    // [probe][wr][col] col-max partials
  __shared__ float rmF[4][192];       // [probe][row] final row-max
  __shared__ float red[16];
  __shared__ float red2[8];

  const int tid = threadIdx.x;
  const int lane = tid & 63;
  const int wid = tid >> 6;          // gal row group: rows wid*48..+47
  const int q = lane >> 4;
  const int r16 = lane & 15;
  const int swz = (r16 & 7) << 4;

  const int g = blockIdx.x >> 4;
  const int pc = blockIdx.x & 15;    // 4 probes per block

  // persistent gallery A-frags: row = wid*48 + m*16 + r16
  const char* gbase = (const char*)(galT + (size_t)g * HW * NC);
  short8 a[3][4];
  #pragma unroll
  for (int m = 0; m < 3; ++m)
    #pragma unroll
    for (int ks = 0; ks < 4; ++ks)
      a[m][ks] = *(const short8*)(gbase + (wid * 48 + m * 16 + r16) * 256 + ks * 64 + q * 16);

  const float w0 = fc_w[tid];                          // feat j = tid
  const float w1 = (tid < 128) ? fc_w[256 + tid] : 0.f; // feat j = 256+tid

  const char* pT = (const char*)probT + (size_t)(pc * 4) * 49152;

  // prologue: stage quarter 0
  #pragma unroll
  for (int ch = 0; ch < 3; ++ch)
    gl_lds16(pT + ch * 4096 + wid * 1024 + lane * 16,
             &ldsP[0][ch * 4096 + wid * 1024]);

  float rm[3][4];
  const f32x4 zz = (f32x4){0.f, 0.f, 0.f, 0.f};

  for (int t = 0; t < 16; ++t) {
    const int qc = t & 3;            // quarter within probe
    const int pi = t >> 2;           // probe index within block
    __syncthreads();                 // prefetch(t) landed; buf[t&1] free of t-2 readers

    if (t + 1 < 16) {                // async prefetch next quarter
      const char* src = pT + (size_t)(t + 1) * QTB;
      char* dst = ldsP[(t + 1) & 1];
      #pragma unroll
      for (int ch = 0; ch < 3; ++ch)
        gl_lds16(src + ch * 4096 + wid * 1024 + lane * 16,
                 dst + ch * 4096 + wid * 1024);
    }
    const char* cur = ldsP[t & 1];

    __builtin_amdgcn_s_setprio(1);
    f32x4 acc[3][3];
    #pragma unroll
    for (int n = 0; n < 3; ++n) {
      const char* rowB = cur + (n * 16 + r16) * 256;
      #pragma unroll
      for (int ks = 0; ks < 4; ++ks) {
        short8 bf = *(const short8*)(rowB + ((ks * 64 + q * 16) ^ swz));
        #pragma unroll
        for (int m = 0; m < 3; ++m)
          acc[m][n] = __builtin_amdgcn_mfma_f32_16x16x32_bf16(
              a[m][ks], bf, (ks == 0) ? zz : acc[m][n], 0, 0, 0);
      }
    }
    __builtin_amdgcn_s_setprio(0);

    // col-max over this wave's 48 rows (fold m,j in-lane; q via shfl)
    #pragma unroll
    for (int n = 0; n < 3; ++n) {
      float m0 = max3f(acc[0][n][0], acc[0][n][1], acc[0][n][2]);
      float m1 = max3f(acc[0][n][3], acc[1][n][0], acc[1][n][1]);
      float m2 = max3f(acc[1][n][2], acc[1][n][3], acc[2][n][0]);
      float m3 = max3f(acc[2][n][1], acc[2][n][2], acc[2][n][3]);
      float cm = max3f(m0, m1, m2);
      cm = fmaxf(cm, m3);
      cm = fmaxf(cm, __shfl_xor(cm, 16));
      cm = fmaxf(cm, __shfl_xor(cm, 32));
      if (lane < 16) cmP[pi][wid][qc * 48 + n * 16 + r16] = cm;
    }
    // row-max: fold over n in-lane, carry across quarters
    #pragma unroll
    for (int m = 0; m < 3; ++m)
      #pragma unroll
      for (int j = 0; j < 4; ++j) {
        float v = max3f(acc[m][0][j], acc[m][1][j], acc[m][2][j]);
        rm[m][j] = (qc == 0) ? v : fmaxf(rm[m][j], v);
      }
    if (qc == 3) {                   // finish: 16-lane DPP fold, publish
      #pragma unroll
      for (int m = 0; m < 3; ++m)
        #pragma unroll
        for (int j = 0; j < 4; ++j) {
          float v = ror16_max(rm[m][j]);
          if (r16 == j) rmF[pi][wid * 48 + m * 16 + q * 4 + j] = v;
        }
    }
  }

  __syncthreads();

  // ---- single combine phase: stats + W for all 4 probes ----
  float s_acc = 0.f, q_acc = 0.f;
  float wp[4];
  #pragma unroll
  for (int pi = 0; pi < 4; ++pi) {
    float w = 0.f;
    float v0;
    if (tid < 192) {
      float c01 = fmaxf(cmP[pi][0][tid], cmP[pi][1][tid]);
      v0 = max3f(c01, cmP[pi][2][tid], cmP[pi][3][tid]);
    } else {
      v0 = rmF[pi][tid - 192];       // feat j = tid (row tid-192)
    }
    s_acc += v0; q_acc += v0 * v0; w += v0 * w0;
    if (tid < 128) {
      float v1 = rmF[pi][tid + 64];  // feat j = 256+tid (row tid+64)
      s_acc += v1; q_acc += v1 * v1; w += v1 * w1;
    }
    #pragma unroll
    for (int msk = 1; msk < 64; msk <<= 1) w += __shfl_xor(w, msk);
    wp[pi] = w;
  }
  if (lane == 0) {
    #pragma unroll
    for (int pi = 0; pi < 4; ++pi) red[pi * 4 + wid] = wp[pi];
  }
  #pragma unroll
  for (int msk = 1; msk < 64; msk <<= 1) {
    s_acc += __shfl_xor(s_acc, msk);
    q_acc += __shfl_xor(q_acc, msk);
  }
  if (lane == 0) { red2[wid] = s_acc; red2[4 + wid] = q_acc; }
  __syncthreads();
  if (tid < 4)
    Wout[(pc * 4 + tid) * 64 + g] =
        red[tid * 4] + red[tid * 4 + 1] + red[tid * 4 + 2] + red[tid * 4 + 3];
  if (tid == 0) {
    sPart[blockIdx.x] = red2[0] + red2[1] + red2[2] + red2[3];
    qPart[blockIdx.x] = red2[4] + red2[5] + red2[6] + red2[7];
  }
}

// ---------------------------------------------------------------------------
// Finalize: exact BN -> fc -> BN chain. One block, 1024 threads.
// ---------------------------------------------------------------------------
__device__ __forceinline__ float block_sum(float v, float* rbuf, float* bc, int nw) {
  int t = threadIdx.x, lane = t & 63, wid = t >> 6;
  #pragma unroll
  for (int m = 1; m < 64; m <<= 1) v += __shfl_xor(v, m);
  if (lane == 0) rbuf[wid] = v;
  __syncthreads();
  if (t == 0) {
    float r = 0.f;
    for (int i = 0; i < nw; ++i) r += rbuf[i];
    bc[0] = r;
  }
  __syncthreads();
  float res = bc[0];
  __syncthreads();
  return res;
}

__global__ __launch_bounds__(1024)
void finalize_kernel(const float* __restrict__ Wv,
                     const float* __restrict__ sPart,
                     const float* __restrict__ qPart,
                     const float* __restrict__ fc_w,
                     const float* __restrict__ fc_b,
                     const float* __restrict__ bn_g,
                     const float* __restrict__ bn_b,
                     const float* __restrict__ lbn_g,
                     const float* __restrict__ lbn_b,
                     float* __restrict__ out) {
  __shared__ float rbuf[16];
  __shared__ float bc[1];
  const int t = threadIdx.x;

  float S = block_sum(sPart[t], rbuf, bc, 16);
  float Q = block_sum(qPart[t], rbuf, bc, 16);
  float SW = block_sum((t < 384) ? fc_w[t] : 0.f, rbuf, bc, 16);

  const float Nf = 4096.0f * 384.0f;
  float mu = S / Nf;
  float var = Q / Nf - mu * mu;
  float istd = rsqrtf(var + KEPS);
  float cA = istd * bn_g[0];
  float off = bn_b[0] * SW + fc_b[0] - cA * mu * SW;

  float l[4];
  float ls = 0.f;
  #pragma unroll
  for (int i = 0; i < 4; ++i) {
    int n = t + i * 1024;
    l[i] = cA * Wv[n] + off;
    ls += l[i];
  }
  float LS = block_sum(ls, rbuf, bc, 16);
  float lmu = LS / 4096.0f;
  float lq = 0.f;
  #pragma unroll
  for (int i = 0; i < 4; ++i) { float d = l[i] - lmu; lq += d * d; }
  float LQ = block_sum(lq, rbuf, bc, 16);
  float lvar = LQ / 4096.0f;
  float sc = lbn_g[0] * rsqrtf(lvar + KEPS);
  float lb = lbn_b[0];
  #pragma unroll
  for (int i = 0; i < 4; ++i) {
    int n = t + i * 1024;
    out[n] = (l[i] - lmu) * sc + lb;
  }
}

// ---------------------------------------------------------------------------
extern "C" void kernel_launch(void* const* d_in, const int* in_sizes, int n_in,
                              void* d_out, int out_size, void* d_ws, size_t ws_size,
                              hipStream_t stream) {
  const float* prob  = (const float*)d_in[0];
  const float* gal   = (const float*)d_in[1];
  const float* bn_g  = (const float*)d_in[2];
  const float* bn_b  = (const float*)d_in[3];
  const float* fc_w  = (const float*)d_in[4];
  const float* fc_b  = (const float*)d_in[5];
  const float* lbn_g = (const float*)d_in[6];
  const float* lbn_b = (const float*)d_in[7];
  float* out = (float*)d_out;

  char* ws = (char*)d_ws;
  unsigned short* probT = (unsigned short*)(ws);            // 3,145,728 B
  unsigned short* galT  = (unsigned short*)(ws + 3145728);  // 3,145,728 B
  float* Wv    = (float*)(ws + 6291456);                    // 16384 B
  float* sPart = (float*)(ws + 6307840);                    // 4096 B
  float* qPart = (float*)(ws + 6311936);                    // 4096 B

  prep_kernel<<<512, 256, 0, stream>>>(prob, gal, probT, galT);
  pair_kernel<<<1024, 256, 0, stream>>>(galT, probT, fc_w, Wv, sPart, qPart);
  finalize_kernel<<<1, 1024, 0, stream>>>(Wv, sPart, qPart, fc_w, fc_b,
                                          bn_g, bn_b, lbn_g, lbn_b, out);
}